// Round 1
// baseline (1364.871 us; speedup 1.0000x reference)
//
#include <hip/hip_runtime.h>

#define L2E 1.44269504088896340736f

// ---- workspace layout (bytes) ----
// [0,32)            int   cnt[8]          (barrier counters, memset 0)
// [256,16640)       float gPred[8*512]    (memset 0 -> initial prev_pred)
// [16896,82432)     float gSP[8*16*128]   (partial scores)
// [82432,84480)     float gEmbWo[512]
// [131072,+6.29MB)  float gXW[1024*1536]  (X@[Ua|Uo|Co])

__device__ __forceinline__ float ld_agent(float* p) {
  return __hip_atomic_load(p, __ATOMIC_RELAXED, __HIP_MEMORY_SCOPE_AGENT);
}
__device__ __forceinline__ void st_agent(float* p, float v) {
  __hip_atomic_store(p, v, __ATOMIC_RELAXED, __HIP_MEMORY_SCOPE_AGENT);
}

__device__ __forceinline__ void group_barrier(int* cnt, int target) {
  __syncthreads();
  if (threadIdx.x == 0) {
    __hip_atomic_fetch_add(cnt, 1, __ATOMIC_RELEASE, __HIP_MEMORY_SCOPE_AGENT);
    while (__hip_atomic_load(cnt, __ATOMIC_ACQUIRE, __HIP_MEMORY_SCOPE_AGENT) < target) { }
  }
  __syncthreads();
}

// ---------------- precompute GEMM: XW[1024][1536] = A[1024][512] @ [Ua|Uo|Co] ----------------
__global__ __launch_bounds__(256) void gemm_pre(
    const float* __restrict__ A, const float* __restrict__ Ua,
    const float* __restrict__ Uo, const float* __restrict__ Co,
    float* __restrict__ XW)
{
  __shared__ float sA[64][33];
  __shared__ float sB[32][68];
  const int r0 = blockIdx.x * 64;
  const int c0 = blockIdx.y * 64;
  const float* Wm; int cc0;
  if (c0 < 512)       { Wm = Ua; cc0 = c0; }
  else if (c0 < 1024) { Wm = Uo; cc0 = c0 - 512; }
  else                { Wm = Co; cc0 = c0 - 1024; }
  const int tid = threadIdx.x;
  const int ty4 = (tid >> 4) * 4;
  const int tx4 = (tid & 15) * 4;
  float acc[4][4] = {};
  for (int k0 = 0; k0 < 512; k0 += 32) {
    for (int t4 = tid; t4 < 512; t4 += 256) {
      int row = t4 >> 3, kq = (t4 & 7) << 2;
      float4 v = *reinterpret_cast<const float4*>(&A[(size_t)(r0 + row) * 512 + k0 + kq]);
      sA[row][kq] = v.x; sA[row][kq + 1] = v.y; sA[row][kq + 2] = v.z; sA[row][kq + 3] = v.w;
    }
    for (int t4 = tid; t4 < 512; t4 += 256) {
      int kk = t4 >> 4, cq = (t4 & 15) << 2;
      float4 v = *reinterpret_cast<const float4*>(&Wm[(size_t)(k0 + kk) * 512 + cc0 + cq]);
      sB[kk][cq] = v.x; sB[kk][cq + 1] = v.y; sB[kk][cq + 2] = v.z; sB[kk][cq + 3] = v.w;
    }
    __syncthreads();
    #pragma unroll 8
    for (int kk = 0; kk < 32; ++kk) {
      float a0 = sA[ty4 + 0][kk], a1 = sA[ty4 + 1][kk];
      float a2 = sA[ty4 + 2][kk], a3 = sA[ty4 + 3][kk];
      float4 bv = *reinterpret_cast<const float4*>(&sB[kk][tx4]);
      acc[0][0] += a0 * bv.x; acc[0][1] += a0 * bv.y; acc[0][2] += a0 * bv.z; acc[0][3] += a0 * bv.w;
      acc[1][0] += a1 * bv.x; acc[1][1] += a1 * bv.y; acc[1][2] += a1 * bv.z; acc[1][3] += a1 * bv.w;
      acc[2][0] += a2 * bv.x; acc[2][1] += a2 * bv.y; acc[2][2] += a2 * bv.z; acc[2][3] += a2 * bv.w;
      acc[3][0] += a3 * bv.x; acc[3][1] += a3 * bv.y; acc[3][2] += a3 * bv.z; acc[3][3] += a3 * bv.w;
    }
    __syncthreads();
  }
  for (int i = 0; i < 4; ++i) {
    float4 v = make_float4(acc[i][0], acc[i][1], acc[i][2], acc[i][3]);
    *reinterpret_cast<float4*>(&XW[(size_t)(r0 + ty4 + i) * 1536 + c0 + tx4]) = v;
  }
}

// ---------------- embWo[k] = sum_o emb[k][o] * Wo[o] ----------------
__global__ __launch_bounds__(512) void embwo_kernel(
    const float* __restrict__ emb, const float* __restrict__ Wo,
    float* __restrict__ gEmbWo)
{
  const int lane = threadIdx.x & 63;
  const int wv = threadIdx.x >> 6;
  const int kbase = blockIdx.x * 64 + wv * 8;
  for (int i = 0; i < 8; ++i) {
    const int k = kbase + i;
    float acc = 0.f;
    #pragma unroll
    for (int c = 0; c < 8; ++c) {
      int o = lane + 64 * c;
      acc += emb[(size_t)k * 512 + o] * Wo[o];
    }
    #pragma unroll
    for (int d = 1; d < 64; d <<= 1) acc += __shfl_xor(acc, d);
    if (lane == 0) gEmbWo[k] = acc;
  }
}

// ---------------- the sequential scan: 8 batches x 16 blocks, 512 thr ----------------
__global__ __launch_bounds__(512) void coop_scan(
    const float* __restrict__ Wa, const float* __restrict__ Va,
    const float* __restrict__ Ba, const float* __restrict__ Bo,
    const float* __restrict__ gXW, const float* __restrict__ gEmbWo,
    float* gPred, float* gSP, int* cnt, float* __restrict__ out)
{
  extern __shared__ float smem[];
  float* sWa     = smem;            // [512][32]  Wa[:, oslice]
  float* sUaH    = smem + 16384;    // [128][32]
  float* sICo    = smem + 20480;    // [128][32]
  float* sP1     = smem + 24576;    // [128][32]  (includes Bo)
  float* sS      = smem + 28672;    // [512] sigmoid(pred)
  float* sEmbWo  = smem + 29184;    // [512]
  float* sRed    = smem + 29696;    // [512] scratch
  float* sScores = smem + 30208;    // [128]
  float* sSm     = smem + 30336;    // [128]
  float* sVa     = smem + 30464;    // [32]
  float* sWaS    = smem + 30496;    // [32]

  const int tid = threadIdx.x;
  const int lane = tid & 63;
  const int wv = tid >> 6;
  const int b = blockIdx.x & 7;   // batch
  const int j = blockIdx.x >> 3;  // o-slice group
  const int obase = j * 32;
  int* bcnt = cnt + b;

  // ---- prologue: load persistent slices ----
  for (int idx = tid; idx < 512 * 32; idx += 512) {
    int k = idx >> 5, oo = idx & 31;
    sWa[idx] = Wa[(size_t)k * 512 + obase + oo];
  }
  for (int idx = tid; idx < 128 * 32; idx += 512) {
    int tt = idx >> 5, oo = idx & 31;
    int col = obase + oo;
    const float* rowp = gXW + (size_t)(b * 128 + tt) * 1536;
    sUaH[idx] = rowp[col] + Ba[col];
    sICo[idx] = rowp[1024 + col];
    int tprev = (tt + 127) & 127;
    sP1[idx] = gXW[(size_t)(b * 128 + tprev) * 1536 + 512 + col] + Bo[col];
  }
  if (tid < 32) sVa[tid] = Va[obase + tid];
  sEmbWo[tid] = gEmbWo[tid];
  __syncthreads();

  float p = 0.f;      // this thread's element of prev_pred (index tid, batch b)
  int bseq = 0;

  for (int t = 0; t < 128; ++t) {
    // ---- phase a: sigmoid + softmax-O stats + WoY (redundant per block) ----
    sS[tid] = 1.f / (1.f + exp2f(-p * L2E));
    float m = p;
    #pragma unroll
    for (int d = 1; d < 64; d <<= 1) m = fmaxf(m, __shfl_xor(m, d));
    if (lane == 0) sRed[wv] = m;
    __syncthreads();
    float mm = sRed[0];
    #pragma unroll
    for (int i = 1; i < 8; ++i) mm = fmaxf(mm, sRed[i]);
    float ee = exp2f((p - mm) * L2E);
    float dd = ee * sEmbWo[tid];
    #pragma unroll
    for (int d = 1; d < 64; d <<= 1) { ee += __shfl_xor(ee, d); dd += __shfl_xor(dd, d); }
    if (lane == 0) { sRed[8 + wv] = ee; sRed[16 + wv] = dd; }
    __syncthreads();
    float den = 0.f, num = 0.f;
    #pragma unroll
    for (int i = 0; i < 8; ++i) { den += sRed[8 + i]; num += sRed[16 + i]; }
    const float WoY = num / den;
    __syncthreads();  // protect sRed before reuse

    // ---- phase b: WaS[oslice] = sum_k s[k] * Wa[k, oslice] ----
    {
      const int kg = tid >> 5, oo = tid & 31;
      const int kb = kg * 32;
      float acc = 0.f;
      #pragma unroll 8
      for (int i = 0; i < 32; ++i) acc += sS[kb + i] * sWa[(size_t)(kb + i) * 32 + oo];
      sRed[tid] = acc;
    }
    __syncthreads();
    if (tid < 32) {
      float w = 0.f;
      #pragma unroll
      for (int g = 0; g < 16; ++g) w += sRed[g * 32 + tid];
      sWaS[tid] = w;
    }
    __syncthreads();

    // ---- phase c: partial scores over own o-slice, all 128 timesteps ----
    {
      const int tp = tid >> 2, q = tid & 3;
      const float4* ua4 = reinterpret_cast<const float4*>(sUaH + tp * 32 + q * 8);
      float4 u0 = ua4[0], u1 = ua4[1];
      float uu[8] = {u0.x, u0.y, u0.z, u0.w, u1.x, u1.y, u1.z, u1.w};
      float acc = 0.f;
      #pragma unroll
      for (int i = 0; i < 8; ++i) {
        const int o = q * 8 + i;
        float u = uu[i] + sWaS[o];
        float ex = exp2f(u * (2.f * L2E));
        float th = 1.f - 2.f / (1.f + ex);   // tanh(u)
        acc += th * sVa[o];
      }
      acc += __shfl_xor(acc, 1);
      acc += __shfl_xor(acc, 2);
      if (q == 0) st_agent(gSP + (size_t)(b * 16 + j) * 128 + tp, acc);
    }
    ++bseq; group_barrier(bcnt, 16 * bseq);

    // ---- phase e: gather partial scores, softmax over T ----
    if (tid < 128) {
      float sc = 0.f;
      #pragma unroll
      for (int i = 0; i < 16; ++i) sc += ld_agent(gSP + (size_t)(b * 16 + i) * 128 + tid);
      sScores[tid] = sc;
    }
    __syncthreads();
    float v = (tid < 128) ? sScores[tid] : -1e30f;
    float mt = v;
    #pragma unroll
    for (int d = 1; d < 64; d <<= 1) mt = fmaxf(mt, __shfl_xor(mt, d));
    if (lane == 0) sRed[wv] = mt;
    __syncthreads();
    float mm2 = fmaxf(sRed[0], sRed[1]);
    float ev = (tid < 128) ? exp2f((v - mm2) * L2E) : 0.f;
    float sv = ev;
    #pragma unroll
    for (int d = 1; d < 64; d <<= 1) sv += __shfl_xor(sv, d);
    if (lane == 0) sRed[8 + wv] = sv;
    __syncthreads();
    float dsum = sRed[8] + sRed[9];
    if (tid < 128) sSm[tid] = ev / dsum;
    __syncthreads();

    // ---- phase f: pred[oslice] = WoY + P1[t,o] + sum_t' sm[t'] * ICo[t',o] ----
    {
      const int tg = tid >> 5, oo = tid & 31;
      const int tb = tg * 8;
      float acc = 0.f;
      #pragma unroll
      for (int i = 0; i < 8; ++i) acc += sSm[tb + i] * sICo[(size_t)(tb + i) * 32 + oo];
      sRed[tid] = acc;
    }
    __syncthreads();
    if (tid < 32) {
      float c = 0.f;
      #pragma unroll
      for (int g = 0; g < 16; ++g) c += sRed[g * 32 + tid];
      float pr = WoY + sP1[t * 32 + tid] + c;
      out[(size_t)(b * 128 + t) * 512 + obase + tid] = pr;
      st_agent(gPred + b * 512 + obase + tid, pr);
    }
    ++bseq; group_barrier(bcnt, 16 * bseq);
    p = ld_agent(gPred + b * 512 + tid);
  }
}

extern "C" void kernel_launch(void* const* d_in, const int* in_sizes, int n_in,
                              void* d_out, int out_size, void* d_ws, size_t ws_size,
                              hipStream_t stream)
{
  const float* inputs = (const float*)d_in[0];
  const float* Wa  = (const float*)d_in[1];
  const float* Ua  = (const float*)d_in[2];
  const float* Va  = (const float*)d_in[3];
  const float* Ba  = (const float*)d_in[4];
  const float* Wo  = (const float*)d_in[5];
  const float* Uo  = (const float*)d_in[6];
  const float* Co  = (const float*)d_in[7];
  const float* Bo  = (const float*)d_in[8];
  const float* emb = (const float*)d_in[9];
  float* out = (float*)d_out;

  char* ws = (char*)d_ws;
  int*   cnt    = (int*)(ws + 0);
  float* gPred  = (float*)(ws + 256);
  float* gSP    = (float*)(ws + 16896);
  float* gEmbWo = (float*)(ws + 82432);
  float* gXW    = (float*)(ws + 131072);

  // zero barrier counters + initial pred
  hipMemsetAsync(d_ws, 0, 16640, stream);

  dim3 gg(16, 24);
  gemm_pre<<<gg, 256, 0, stream>>>(inputs, Ua, Uo, Co, gXW);
  embwo_kernel<<<8, 512, 0, stream>>>(emb, Wo, gEmbWo);

  const int smem_bytes = 30528 * 4;  // 122112 B dynamic LDS
  hipFuncSetAttribute((const void*)coop_scan,
                      hipFuncAttributeMaxDynamicSharedMemorySize, smem_bytes);
  coop_scan<<<128, 512, smem_bytes, stream>>>(Wa, Va, Ba, Bo, gXW, gEmbWo,
                                              gPred, gSP, cnt, out);
}

// Round 3
// 1333.566 us; speedup vs baseline: 1.0235x; 1.0235x over previous
//
#include <hip/hip_runtime.h>

#define L2E 1.44269504088896340736f

// ---- workspace layout (bytes) ----
// [0,2048)          int   cntS[8]  (256B stride, memset 0)
// [2048,4096)       int   cntP[8]  (256B stride, memset 0)
// [8192,40960)      float slotP[2][8][512]       (pred exchange, ring-2)
// [40960,106496)    float slotS[2][8][16][128]   (score partials, ring-2)
// [106496,108544)   float gEmbWo[512]
// [131072,+6.29MB)  float gXW[1024*1536]  (X@[Ua|Uo|Co])

__device__ __forceinline__ float ld_agent(const float* p) {
  return __hip_atomic_load(p, __ATOMIC_RELAXED, __HIP_MEMORY_SCOPE_AGENT);
}
__device__ __forceinline__ void st_agent(float* p, float v) {
  __hip_atomic_store(p, v, __ATOMIC_RELAXED, __HIP_MEMORY_SCOPE_AGENT);
}

// ---------------- precompute GEMM: XW[1024][1536] = A[1024][512] @ [Ua|Uo|Co] ----------------
__global__ __launch_bounds__(256) void gemm_pre(
    const float* __restrict__ A, const float* __restrict__ Ua,
    const float* __restrict__ Uo, const float* __restrict__ Co,
    float* __restrict__ XW)
{
  __shared__ float sA[64][33];
  __shared__ float sB[32][68];
  const int r0 = blockIdx.x * 64;
  const int c0 = blockIdx.y * 64;
  const float* Wm; int cc0;
  if (c0 < 512)       { Wm = Ua; cc0 = c0; }
  else if (c0 < 1024) { Wm = Uo; cc0 = c0 - 512; }
  else                { Wm = Co; cc0 = c0 - 1024; }
  const int tid = threadIdx.x;
  const int ty4 = (tid >> 4) * 4;
  const int tx4 = (tid & 15) * 4;
  float acc[4][4] = {};
  for (int k0 = 0; k0 < 512; k0 += 32) {
    for (int t4 = tid; t4 < 512; t4 += 256) {
      int row = t4 >> 3, kq = (t4 & 7) << 2;
      float4 v = *reinterpret_cast<const float4*>(&A[(size_t)(r0 + row) * 512 + k0 + kq]);
      sA[row][kq] = v.x; sA[row][kq + 1] = v.y; sA[row][kq + 2] = v.z; sA[row][kq + 3] = v.w;
    }
    for (int t4 = tid; t4 < 512; t4 += 256) {
      int kk = t4 >> 4, cq = (t4 & 15) << 2;
      float4 v = *reinterpret_cast<const float4*>(&Wm[(size_t)(k0 + kk) * 512 + cc0 + cq]);
      sB[kk][cq] = v.x; sB[kk][cq + 1] = v.y; sB[kk][cq + 2] = v.z; sB[kk][cq + 3] = v.w;
    }
    __syncthreads();
    #pragma unroll 8
    for (int kk = 0; kk < 32; ++kk) {
      float a0 = sA[ty4 + 0][kk], a1 = sA[ty4 + 1][kk];
      float a2 = sA[ty4 + 2][kk], a3 = sA[ty4 + 3][kk];
      float4 bv = *reinterpret_cast<const float4*>(&sB[kk][tx4]);
      acc[0][0] += a0 * bv.x; acc[0][1] += a0 * bv.y; acc[0][2] += a0 * bv.z; acc[0][3] += a0 * bv.w;
      acc[1][0] += a1 * bv.x; acc[1][1] += a1 * bv.y; acc[1][2] += a1 * bv.z; acc[1][3] += a1 * bv.w;
      acc[2][0] += a2 * bv.x; acc[2][1] += a2 * bv.y; acc[2][2] += a2 * bv.z; acc[2][3] += a2 * bv.w;
      acc[3][0] += a3 * bv.x; acc[3][1] += a3 * bv.y; acc[3][2] += a3 * bv.z; acc[3][3] += a3 * bv.w;
    }
    __syncthreads();
  }
  for (int i = 0; i < 4; ++i) {
    float4 v = make_float4(acc[i][0], acc[i][1], acc[i][2], acc[i][3]);
    *reinterpret_cast<float4*>(&XW[(size_t)(r0 + ty4 + i) * 1536 + c0 + tx4]) = v;
  }
}

// ---------------- embWo[k] = sum_o emb[k][o] * Wo[o] ----------------
__global__ __launch_bounds__(512) void embwo_kernel(
    const float* __restrict__ emb, const float* __restrict__ Wo,
    float* __restrict__ gEmbWo)
{
  const int lane = threadIdx.x & 63;
  const int wv = threadIdx.x >> 6;
  const int kbase = blockIdx.x * 64 + wv * 8;
  for (int i = 0; i < 8; ++i) {
    const int k = kbase + i;
    float acc = 0.f;
    #pragma unroll
    for (int c = 0; c < 8; ++c) {
      int o = lane + 64 * c;
      acc += emb[(size_t)k * 512 + o] * Wo[o];
    }
    #pragma unroll
    for (int d = 1; d < 64; d <<= 1) acc += __shfl_xor(acc, d);
    if (lane == 0) gEmbWo[k] = acc;
  }
}

// ---------------- the sequential scan: 8 batches x 16 blocks, 256 thr ----------------
__global__ __launch_bounds__(256) void coop_scan(
    const float* __restrict__ Wa, const float* __restrict__ Va,
    const float* __restrict__ Ba, const float* __restrict__ Bo,
    const float* __restrict__ gXW, const float* __restrict__ gEmbWo,
    float* slotP, float* slotS, int* cntS, int* cntP, float* __restrict__ out)
{
  extern __shared__ float smem[];
  float* sWa   = smem;             // [512][32]   Wa[:, oslice]
  float* sUaHT = smem + 16384;     // [32][129]   UaH transposed (+Ba)
  float* sICo  = smem + 20512;     // [128][32]
  float* sP1   = smem + 24608;     // [128][32]   (incl Bo)
  float* sPred = smem + 28704;     // [512] full pred
  float* sS    = smem + 29216;     // [512] sigmoid(pred)
  float* sEmb  = smem + 29728;     // [512] embWo
  float* sVa   = smem + 30240;     // [32]
  float* sWaS  = smem + 30272;     // [32]
  float* sSm   = smem + 30304;     // [128] raw exp(score)
  float* sRedB = smem + 30432;     // [8][32]
  float* sRed  = smem + 30688;     // [16]

  const int tid = threadIdx.x;
  const int lane = tid & 63;
  const int wv = tid >> 6;        // 0..3
  const int b = blockIdx.x & 7;   // batch -> XCD-local group
  const int j = blockIdx.x >> 3;  // o-slice 0..15
  const int obase = j * 32;
  int* mycntS = cntS + b * 64;    // 256 B apart
  int* mycntP = cntP + b * 64;

  // ---- prologue ----
  for (int idx = tid; idx < 512 * 32; idx += 256) {
    int k = idx >> 5, oo = idx & 31;
    sWa[idx] = Wa[(size_t)k * 512 + obase + oo];
  }
  for (int idx = tid; idx < 128 * 32; idx += 256) {
    int tt = idx >> 5, oo = idx & 31;
    int col = obase + oo;
    const float* rowp = gXW + (size_t)(b * 128 + tt) * 1536;
    sUaHT[oo * 129 + tt] = rowp[col] + Ba[col];
    sICo[tt * 32 + oo] = rowp[1024 + col];
    int tprev = (tt + 127) & 127;
    sP1[tt * 32 + oo] = gXW[(size_t)(b * 128 + tprev) * 1536 + 512 + col] + Bo[col];
  }
  if (tid < 32) sVa[tid] = Va[obase + tid];
  sEmb[tid] = gEmbWo[tid]; sEmb[tid + 256] = gEmbWo[tid + 256];
  sPred[tid] = 0.f; sPred[tid + 256] = 0.f;

  for (int t = 0; t < 128; ++t) {
    __syncthreads();  // (1) sPred ready (prologue or prev-step gather)

    // ---- stage1: sigmoid + softmax-O stats (no max subtraction) ----
    float p1 = sPred[tid], p2 = sPred[tid + 256];
    sS[tid]       = 1.f / (1.f + exp2f(-p1 * L2E));
    sS[tid + 256] = 1.f / (1.f + exp2f(-p2 * L2E));
    float e1 = exp2f(p1 * L2E), e2 = exp2f(p2 * L2E);
    float Ep = e1 + e2;
    float Dp = e1 * sEmb[tid] + e2 * sEmb[tid + 256];
    #pragma unroll
    for (int d = 1; d < 64; d <<= 1) { Ep += __shfl_xor(Ep, d); Dp += __shfl_xor(Dp, d); }
    if (lane == 0) { sRed[wv] = Ep; sRed[4 + wv] = Dp; }
    __syncthreads();  // (2) sS, sRed ready
    const float WoY = (sRed[4] + sRed[5] + sRed[6] + sRed[7])
                    / (sRed[0] + sRed[1] + sRed[2] + sRed[3]);

    // ---- phase b: WaS[oslice] = sum_k s[k]*Wa[k,oslice] ----
    {
      const int o = tid & 31, kg = tid >> 5, kb = kg * 64;
      float acc = 0.f;
      #pragma unroll 16
      for (int i = 0; i < 64; ++i) acc += sS[kb + i] * sWa[(kb + i) * 32 + o];
      sRedB[kg * 32 + o] = acc;
    }
    __syncthreads();  // (3)
    if (tid < 32) {
      float w = 0.f;
      #pragma unroll
      for (int g = 0; g < 8; ++g) w += sRedB[g * 32 + tid];
      sWaS[tid] = w;
    }
    __syncthreads();  // (4)

    // ---- phase c: partial scores over own o-slice, 128 timesteps ----
    {
      const int h = tid & 1, tp = tid >> 1;
      float acc = 0.f;
      #pragma unroll
      for (int i = 0; i < 16; ++i) {
        const int oo = h * 16 + i;
        float u = sUaHT[oo * 129 + tp] + sWaS[oo];
        float ex = exp2f(u * (2.f * L2E));
        acc += (1.f - 2.f / (1.f + ex)) * sVa[oo];   // tanh(u)*Va
      }
      acc += __shfl_xor(acc, 1);
      if (h == 0) st_agent(slotS + (((t & 1) * 8 + b) * 16 + j) * 128 + tp, acc);
    }
    __syncthreads();  // (5) all stores issued
    if (tid == 0) {
      __hip_atomic_fetch_add(mycntS, 1, __ATOMIC_RELEASE, __HIP_MEMORY_SCOPE_AGENT);
      const int tgt = 16 * (t + 1);
      while (__hip_atomic_load(mycntS, __ATOMIC_ACQUIRE, __HIP_MEMORY_SCOPE_AGENT) < tgt) { }
    }
    __syncthreads();  // (6)

    // ---- gather scores + softmax over T (no max subtraction) ----
    if (tid < 128) {
      const float* basep = slotS + ((t & 1) * 8 + b) * 2048 + tid;
      float sc = 0.f;
      #pragma unroll
      for (int jj = 0; jj < 16; ++jj) sc += ld_agent(basep + jj * 128);
      float ev = exp2f(sc * L2E);
      sSm[tid] = ev;
      float sv = ev;
      #pragma unroll
      for (int d = 1; d < 64; d <<= 1) sv += __shfl_xor(sv, d);
      if (lane == 0) sRed[8 + wv] = sv;   // wv in {0,1}
    }
    __syncthreads();  // (7)
    const float rden = 1.f / (sRed[8] + sRed[9]);

    // ---- phase f: pred[oslice] = WoY + P1 + (sum_t' e[t']*ICo)/den ----
    {
      const int o = tid & 31, g = tid >> 5, tb = g * 16;
      float acc = 0.f;
      #pragma unroll
      for (int i = 0; i < 16; ++i) acc += sSm[tb + i] * sICo[(tb + i) * 32 + o];
      sRedB[g * 32 + o] = acc;
    }
    __syncthreads();  // (8)
    if (tid < 32) {
      float c = 0.f;
      #pragma unroll
      for (int g2 = 0; g2 < 8; ++g2) c += sRedB[g2 * 32 + tid];
      float pr = WoY + sP1[t * 32 + tid] + c * rden;
      out[(size_t)(b * 128 + t) * 512 + obase + tid] = pr;
      st_agent(slotP + ((t & 1) * 8 + b) * 512 + obase + tid, pr);
    }
    __syncthreads();  // (9)
    if (tid == 0) {
      __hip_atomic_fetch_add(mycntP, 1, __ATOMIC_RELEASE, __HIP_MEMORY_SCOPE_AGENT);
      const int tgt = 16 * (t + 1);
      while (__hip_atomic_load(mycntP, __ATOMIC_ACQUIRE, __HIP_MEMORY_SCOPE_AGENT) < tgt) { }
    }
    __syncthreads();  // (10)
    const float* pp = slotP + ((t & 1) * 8 + b) * 512;
    sPred[tid] = ld_agent(pp + tid);
    sPred[tid + 256] = ld_agent(pp + tid + 256);
  }
}

extern "C" void kernel_launch(void* const* d_in, const int* in_sizes, int n_in,
                              void* d_out, int out_size, void* d_ws, size_t ws_size,
                              hipStream_t stream)
{
  const float* inputs = (const float*)d_in[0];
  const float* Wa  = (const float*)d_in[1];
  const float* Ua  = (const float*)d_in[2];
  const float* Va  = (const float*)d_in[3];
  const float* Ba  = (const float*)d_in[4];
  const float* Wo  = (const float*)d_in[5];
  const float* Uo  = (const float*)d_in[6];
  const float* Co  = (const float*)d_in[7];
  const float* Bo  = (const float*)d_in[8];
  const float* emb = (const float*)d_in[9];
  float* out = (float*)d_out;

  char* ws = (char*)d_ws;
  int*   cntS   = (int*)(ws + 0);
  int*   cntP   = (int*)(ws + 2048);
  float* slotP  = (float*)(ws + 8192);
  float* slotS  = (float*)(ws + 40960);
  float* gEmbWo = (float*)(ws + 106496);
  float* gXW    = (float*)(ws + 131072);

  // zero barrier counters only
  hipMemsetAsync(d_ws, 0, 4096, stream);

  dim3 gg(16, 24);
  gemm_pre<<<gg, 256, 0, stream>>>(inputs, Ua, Uo, Co, gXW);
  embwo_kernel<<<8, 512, 0, stream>>>(emb, Wo, gEmbWo);

  const int smem_bytes = 30704 * 4;  // 122816 B dynamic LDS
  hipFuncSetAttribute((const void*)coop_scan,
                      hipFuncAttributeMaxDynamicSharedMemorySize, smem_bytes);
  coop_scan<<<128, 256, smem_bytes, stream>>>(Wa, Va, Ba, Bo, gXW, gEmbWo,
                                              slotP, slotS, cntS, cntP, out);
}